// Round 7
// baseline (1159.852 us; speedup 1.0000x reference)
//
#include <hip/hip_runtime.h>
#include <hip/hip_bf16.h>
#include <cstdint>

// Problem constants: B=64, T=512, E=256, H=128, 4H=512.
#define BB 64
#define TT 512
#define EE 256
#define HH 128
#define G4 512

typedef _Float16 half2_t __attribute__((ext_vector_type(2)));
typedef _Float16 f16x4 __attribute__((ext_vector_type(4)));
typedef _Float16 f16x8 __attribute__((ext_vector_type(8)));
typedef float f32x4 __attribute__((ext_vector_type(4)));

#define BC(x) __builtin_bit_cast(half2_t, x)

__device__ __forceinline__ float fdot2f(half2_t a, half2_t b, float c) {
#if defined(__has_builtin)
#if __has_builtin(__builtin_amdgcn_fdot2)
  return __builtin_amdgcn_fdot2(a, b, c, false);
#else
  return c + (float)a[0] * (float)b[0] + (float)a[1] * (float)b[1];
#endif
#else
  return c + (float)a[0] * (float)b[0] + (float)a[1] * (float)b[1];
#endif
}

__device__ __forceinline__ float rcp_(float x) { return __builtin_amdgcn_rcpf(x); }
__device__ __forceinline__ float tanh_(float x) {
  float ax = fabsf(x);
  float e = __expf(-2.f * ax);             // in (0,1], no overflow ever
  float r = (1.f - e) * rcp_(1.f + e);
  return copysignf(r, x);
}

__device__ __forceinline__ float readlane_f(float x, int lane) {
#if defined(__has_builtin)
#if __has_builtin(__builtin_amdgcn_readlane)
  return __builtin_bit_cast(float, __builtin_amdgcn_readlane(__builtin_bit_cast(int, x), lane));
#else
  return __shfl(x, lane);
#endif
#else
  return __shfl(x, lane);
#endif
}

// 64-lane sum via DPP (VALU pipe, not LDS pipe), broadcast via readlane(63).
#if defined(__has_builtin)
#if __has_builtin(__builtin_amdgcn_update_dpp)
#define HAVE_DPP 1
#endif
#endif

__device__ __forceinline__ float wave_sum64_bcast(float x) {
#ifdef HAVE_DPP
#define DPP_ADD(ctrl)                                                          \
  {                                                                            \
    int _t = __builtin_amdgcn_update_dpp(0, __builtin_bit_cast(int, x), ctrl,  \
                                         0xf, 0xf, true);                      \
    x += __builtin_bit_cast(float, _t);                                        \
  }
  DPP_ADD(0x111)  // row_shr:1
  DPP_ADD(0x112)  // row_shr:2
  DPP_ADD(0x114)  // row_shr:4
  DPP_ADD(0x118)  // row_shr:8
  DPP_ADD(0x142)  // row_bcast:15
  DPP_ADD(0x143)  // row_bcast:31
#undef DPP_ADD
  return readlane_f(x, 63);
#else
#pragma unroll
  for (int s = 1; s <= 32; s <<= 1) x += __shfl_xor(x, s);
  return x;
#endif
}

// ---------------------------------------------------------------------------
// Kernel A: trans = row-softmax(transition); W16 = (f16)W_ih
// ---------------------------------------------------------------------------
__global__ __launch_bounds__(128) void prep_kernel(
    const float* __restrict__ transition, const float* __restrict__ W_ih,
    float* __restrict__ trans, _Float16* __restrict__ W16) {
  const int bid = blockIdx.x, t = threadIdx.x;
  if (bid < 128) {
    __shared__ float red[2];
    float v = transition[bid * HH + t];
    float m = v;
#pragma unroll
    for (int s = 32; s >= 1; s >>= 1) m = fmaxf(m, __shfl_xor(m, s));
    if ((t & 63) == 0) red[t >> 6] = m;
    __syncthreads();
    m = fmaxf(red[0], red[1]);
    float e = __expf(v - m);
    float s = e;
#pragma unroll
    for (int k = 32; k >= 1; k >>= 1) s += __shfl_xor(s, k);
    __syncthreads();  // protect red before reuse
    if ((t & 63) == 0) red[t >> 6] = s;
    __syncthreads();
    trans[bid * HH + t] = e * rcp_(red[0] + red[1]);
  } else {
    const int base = (bid - 128) * 1024 + t * 8;  // 131072 total elems
    float4 v0 = *(const float4*)(W_ih + base);
    float4 v1 = *(const float4*)(W_ih + base + 4);
    f16x8 h;
    h[0] = (_Float16)v0.x; h[1] = (_Float16)v0.y;
    h[2] = (_Float16)v0.z; h[3] = (_Float16)v0.w;
    h[4] = (_Float16)v1.x; h[5] = (_Float16)v1.y;
    h[6] = (_Float16)v1.z; h[7] = (_Float16)v1.w;
    *(f16x8*)(W16 + base) = h;
  }
}

// ---------------------------------------------------------------------------
// Kernel B: precomp[m][j] = sum_e inputs[m][e]*W_ih[j][e] + b_ih[j] + b_hh[j]
// M=32768, N=512, K=256.  MFMA f16 16x16x32.  grid (512, 2) x 256 threads.
// ---------------------------------------------------------------------------
__global__ __launch_bounds__(256) void gemm_in(
    const float* __restrict__ A, const _Float16* __restrict__ W16,
    const float* __restrict__ b_ih, const float* __restrict__ b_hh,
    float* __restrict__ out) {
  __shared__ _Float16 As[64][264];  // K=256 + 8 pad (16B-aligned rows)
  const int t = threadIdx.x;
  const int m0 = blockIdx.x * 64;
  const int n0 = blockIdx.y * 256;
  {
    const int c4 = t & 63, r0 = t >> 6;
#pragma unroll
    for (int p = 0; p < 16; ++p) {
      const int row = r0 + 4 * p;
      float4 v = *(const float4*)(A + (size_t)(m0 + row) * EE + c4 * 4);
      f16x4 h;
      h[0] = (_Float16)v.x; h[1] = (_Float16)v.y;
      h[2] = (_Float16)v.z; h[3] = (_Float16)v.w;
      *(f16x4*)&As[row][c4 * 4] = h;
    }
  }
  __syncthreads();
  const int w = t >> 6, L = t & 63;
  const int lrow = L & 15, quad = L >> 4, lk = quad * 8;
  f32x4 acc[4][4] = {};
  const _Float16* Wbase = W16 + (size_t)(n0 + w * 64) * EE;
#pragma unroll
  for (int kc = 0; kc < 8; ++kc) {
    f16x8 a[4], bf[4];
#pragma unroll
    for (int mf = 0; mf < 4; ++mf)
      a[mf] = *(const f16x8*)&As[mf * 16 + lrow][kc * 32 + lk];
#pragma unroll
    for (int nf = 0; nf < 4; ++nf)
      bf[nf] = *(const f16x8*)(Wbase + (size_t)(nf * 16 + lrow) * EE + kc * 32 + lk);
#pragma unroll
    for (int mf = 0; mf < 4; ++mf)
#pragma unroll
      for (int nf = 0; nf < 4; ++nf)
        acc[mf][nf] = __builtin_amdgcn_mfma_f32_16x16x32_f16(a[mf], bf[nf], acc[mf][nf], 0, 0, 0);
  }
#pragma unroll
  for (int nf = 0; nf < 4; ++nf) {
    const int j = n0 + w * 64 + nf * 16 + lrow;  // C/D: col = lane&15
    const float bias = b_ih[j] + b_hh[j];
#pragma unroll
    for (int mf = 0; mf < 4; ++mf) {
#pragma unroll
      for (int r = 0; r < 4; ++r) {  // C/D: row = quad*4 + r
        const int m = m0 + mf * 16 + quad * 4 + r;
        out[(size_t)m * G4 + j] = acc[mf][nf][r] + bias;
      }
    }
  }
}

// ---------------------------------------------------------------------------
// Kernel C: fused LSTM + softmax + CRF forward.  TWO batches per 1024-thread
// block (grid 32); chain cc = t>>9 runs the R4 structure.
// R6 confound fix: __launch_bounds__(1024, 4) — 4 waves/EU = exactly one
// 16-wave block/CU => VGPR cap 128 (R4's identical per-thread code used 104).
// R6's default bounds let the compiler cap at 64 VGPR -> w[64] spilled to
// scratch (WRITE_SIZE 2KB -> 7.8MB, 2x slowdown).  This round measures the
// actual overlap hypothesis: two independent chains per CU fill each other's
// latency bubbles (phase-1 dot chains, ds_reads, phase-3 tails on different
// SIMDs).  Worst case = R4's 475 us (2 steps serialized on half the CUs).
// ---------------------------------------------------------------------------
__global__ __launch_bounds__(1024, 4) void lstm_crf(
    const float* __restrict__ precomp, const float* __restrict__ Whh,
    const float* __restrict__ trans, const int* __restrict__ labels,
    float* __restrict__ out_b) {
  const int t = threadIdx.x;
  const int cc = t >> 9;          // chain (batch) within block
  const int tt = t & 511;         // thread within chain
  const int bb = blockIdx.x * 2 + cc;
  const int g = tt >> 7;          // gate index (i,f,g,o) and CRF K-quarter
  const int j = tt & 127;         // unit index

  __shared__ __align__(16) _Float16 h_lds[2][HH];
  __shared__ __align__(16) _Float16 E_lds[2][HH];
  __shared__ __align__(16) float act[2][G4];    // [chain][gate*128+unit]
  __shared__ __align__(16) float Spart[2][G4];  // [chain][quarter*128+unit]
  __shared__ int lab[2][TT];

  // --- one-time loads -------------------------------------------------------
  half2_t w[64];  // W_hh[tt][0..127] as f16 pairs (full row)
  {
    const float4* wr = (const float4*)(Whh + (size_t)tt * HH);
#pragma unroll
    for (int i = 0; i < 32; ++i) {
      float4 v = wr[i];
      half2_t p0, p1;
      p0[0] = (_Float16)v.x; p0[1] = (_Float16)v.y;
      p1[0] = (_Float16)v.z; p1[1] = (_Float16)v.w;
      w[2 * i] = p0; w[2 * i + 1] = p1;
    }
  }
  // et[a] = exp(trans[g*32+2a][j]), exp(trans[g*32+2a+1][j])
  half2_t et[16];
#pragma unroll
  for (int a = 0; a < 16; ++a) {
    float e0 = __expf(trans[(g * 32 + 2 * a) * HH + j]);
    float e1 = __expf(trans[(g * 32 + 2 * a + 1) * HH + j]);
    half2_t h2; h2[0] = (_Float16)e0; h2[1] = (_Float16)e1;
    et[a] = h2;
  }
  lab[cc][tt] = labels[bb * TT + tt];
  if (tt < HH) { h_lds[cc][tt] = (_Float16)0.f; E_lds[cc][tt] = (_Float16)0.f; }

  // per-chain wave-0 persistent state (units 2*l, 2*l+1 where l = tt)
  float tr0x = 0.f, tr0y = 0.f, tr127x = 0.f, tr127y = 0.f;
  if (tt < 64) {
    float2 v0 = *(const float2*)(trans + 2 * tt);
    float2 v1 = *(const float2*)(trans + 127 * HH + 2 * tt);
    tr0x = v0.x; tr0y = v0.y; tr127x = v1.x; tr127y = v1.y;
  }
  float c0 = 0.f, c1 = 0.f, preA = 0.f, preB = 0.f, mused = 0.f, emit = 0.f;

  const float* pcb = precomp + (size_t)bb * TT * G4 + tt;
  float cbuf[8], nbuf[8];
#pragma unroll
  for (int k = 0; k < 8; ++k) cbuf[k] = pcb[(size_t)k * G4];
  __syncthreads();

#pragma unroll 1
  for (int base = 0; base < TT; base += 8) {
    const bool more = (base + 8 < TT);
    if (more) {
#pragma unroll
      for (int k = 0; k < 8; ++k) nbuf[k] = pcb[(size_t)(base + 8 + k) * G4];
    }
#pragma unroll
    for (int k = 0; k < 8; ++k) {
      const int step = base + k;
      const float cur = cbuf[k];
      // --- phase 1: gate matvec (full K) + CRF quarter dot -----------------
      float a0 = 0.f, a1 = 0.f, a2 = 0.f, a3 = 0.f;
      const float4* hv4 = (const float4*)h_lds[cc];
#pragma unroll
      for (int kc = 0; kc < 16; ++kc) {
        float4 hb = hv4[kc];
        a0 = fdot2f(w[4 * kc + 0], BC(hb.x), a0);
        a1 = fdot2f(w[4 * kc + 1], BC(hb.y), a1);
        a2 = fdot2f(w[4 * kc + 2], BC(hb.z), a2);
        a3 = fdot2f(w[4 * kc + 3], BC(hb.w), a3);
      }
      float s0 = 0.f, s1 = 0.f;
      const float4* ev4 = (const float4*)E_lds[cc] + g * 4;
#pragma unroll
      for (int ec = 0; ec < 4; ++ec) {
        float4 eb = ev4[ec];
        s0 = fdot2f(et[4 * ec + 0], BC(eb.x), s0);
        s1 = fdot2f(et[4 * ec + 1], BC(eb.y), s1);
        s0 = fdot2f(et[4 * ec + 2], BC(eb.z), s0);
        s1 = fdot2f(et[4 * ec + 3], BC(eb.w), s1);
      }
      const float gate = cur + ((a0 + a1) + (a2 + a3));
      // branchless activation: sigmoid for i,f,o; tanh for g (g==2)
      const bool isg = (g == 2);
      const float yy = isg ? (-2.f * fabsf(gate)) : (-gate);
      const float exv = __expf(yy);
      const float num = isg ? (1.f - exv) : 1.f;
      float av = num * rcp_(1.f + exv);
      av = isg ? copysignf(av, gate) : av;
      act[cc][tt] = av;            // gate-major: lane-consecutive, no conflict
      Spart[cc][tt] = s0 + s1;
      __syncthreads();  // A
      // --- phase 3 (per-chain wave: tt<64): cell, softmax, CRF -------------
      if (tt < 64) {
        const float2* a2p = (const float2*)act[cc];
        float2 I = a2p[tt], F = a2p[64 + tt], G = a2p[128 + tt], O = a2p[192 + tt];
        const float2* s2p = (const float2*)Spart[cc];
        float2 Sq0 = s2p[tt], Sq1 = s2p[64 + tt], Sq2 = s2p[128 + tt], Sq3 = s2p[192 + tt];
        c0 = F.x * c0 + I.x * G.x;
        c1 = F.y * c1 + I.y * G.y;
        const float h0 = O.x * tanh_(c0), h1 = O.y * tanh_(c1);
        const float e0 = __expf(h0), e1 = __expf(h1);  // |h|<1: no max-sub
        const float denom = wave_sum64_bcast(e0 + e1);
        const float rinv = rcp_(denom);
        const float p0 = e0 * rinv, p1 = e1 * rinv;
        const float Sa = (Sq0.x + Sq1.x) + (Sq2.x + Sq3.x);
        const float Sb = (Sq0.y + Sq1.y) + (Sq2.y + Sq3.y);
        const float lgSa = __logf(Sa), lgSb = __logf(Sb);
        const float lgS0 = readlane_f(lgSa, 0);      // unit 0's log S
        const int lb = lab[cc][step];
        const float Mnext = (step == 0) ? 0.f : (mused + lgS0);
        preA = p0 + ((step == 0) ? tr0x : (mused + lgSa));
        preB = p1 + ((step == 0) ? tr0y : (mused + lgSb));
        if (2 * tt == lb) emit += p0;
        if (2 * tt + 1 == lb) emit += p1;
        half2_t Eh;
        Eh[0] = (_Float16)__expf(preA - Mnext);  // bounded ~[0.37, 7.4]
        Eh[1] = (_Float16)__expf(preB - Mnext);
        *(half2_t*)&E_lds[cc][2 * tt] = Eh;
        half2_t Hh;
        Hh[0] = (_Float16)h0; Hh[1] = (_Float16)h1;
        *(half2_t*)&h_lds[cc][2 * tt] = Hh;
        mused = Mnext;
      }
      __syncthreads();  // C
    }
    if (more) {
#pragma unroll
      for (int k = 0; k < 8; ++k) cbuf[k] = nbuf[k];
    }
  }
  // --- epilogue (per-chain wave): Ps = LSE(pre+trans[127]); out = Ps-emit --
  if (tt < 64) {
    float v0 = preA + tr127x, v1 = preB + tr127y;
    float m = fmaxf(v0, v1);
#pragma unroll
    for (int s = 1; s <= 32; s <<= 1) m = fmaxf(m, __shfl_xor(m, s));
    float ex = __expf(v0 - m) + __expf(v1 - m);
    float em = emit;
#pragma unroll
    for (int s = 1; s <= 32; s <<= 1) {
      ex += __shfl_xor(ex, s);
      em += __shfl_xor(em, s);
    }
    if (tt == 0) out_b[bb] = m + __logf(ex) - em;
  }
}

// ---------------------------------------------------------------------------
// Kernel D: total = sum_b out_b[b] - sum_{b,t<511} trans[l_t][l_{t+1}]
// ---------------------------------------------------------------------------
__global__ __launch_bounds__(512) void finalize_kernel(
    const float* __restrict__ trans, const int* __restrict__ labels,
    const float* __restrict__ out_b, float* __restrict__ d_out) {
  const int t = threadIdx.x;
  float a = 0.f;
  if (t < TT - 1) {
    for (int b = 0; b < BB; ++b) {
      const int l0 = labels[b * TT + t];
      const int l1 = labels[b * TT + t + 1];
      a += trans[l0 * HH + l1];
    }
  }
  float x = ((t < BB) ? out_b[t] : 0.f) - a;
  __shared__ float red[8];
#pragma unroll
  for (int s = 32; s >= 1; s >>= 1) x += __shfl_xor(x, s);
  if ((t & 63) == 0) red[t >> 6] = x;
  __syncthreads();
  if (t == 0) {
    float s = 0.f;
#pragma unroll
    for (int i = 0; i < 8; ++i) s += red[i];
    d_out[0] = s;
  }
}

// ---------------------------------------------------------------------------
extern "C" void kernel_launch(void* const* d_in, const int* in_sizes, int n_in,
                              void* d_out, int out_size, void* d_ws, size_t ws_size,
                              hipStream_t stream) {
  const float* inputs = (const float*)d_in[0];      // (64,512,256) f32
  const int* labels = (const int*)d_in[1];          // (64,512) i32
  const float* W_ih = (const float*)d_in[2];        // (512,256) f32
  const float* W_hh = (const float*)d_in[3];        // (512,128) f32
  const float* b_ih = (const float*)d_in[4];        // (512,) f32
  const float* b_hh = (const float*)d_in[5];        // (512,) f32
  const float* transition = (const float*)d_in[6];  // (128,128) f32

  char* ws = (char*)d_ws;
  float* precomp = (float*)ws;                           // 64 MiB
  float* trans = (float*)(ws + 67108864);                // 64 KiB
  _Float16* W16 = (_Float16*)(ws + 67108864 + 65536);    // 256 KiB
  float* out_b = (float*)(ws + 67108864 + 65536 + 262144);

  prep_kernel<<<256, 128, 0, stream>>>(transition, W_ih, trans, W16);
  gemm_in<<<dim3(512, 2), 256, 0, stream>>>(inputs, W16, b_ih, b_hh, precomp);
  lstm_crf<<<32, 1024, 0, stream>>>(precomp, W_hh, trans, labels, out_b);
  finalize_kernel<<<1, 512, 0, stream>>>(trans, labels, out_b, (float*)d_out);
}

// Round 8
// 579.298 us; speedup vs baseline: 2.0022x; 2.0022x over previous
//
#include <hip/hip_runtime.h>
#include <hip/hip_bf16.h>
#include <cstdint>

// Problem constants: B=64, T=512, E=256, H=128, 4H=512.
#define BB 64
#define TT 512
#define EE 256
#define HH 128
#define G4 512

typedef _Float16 half2_t __attribute__((ext_vector_type(2)));
typedef _Float16 f16x4 __attribute__((ext_vector_type(4)));
typedef _Float16 f16x8 __attribute__((ext_vector_type(8)));
typedef float f32x4 __attribute__((ext_vector_type(4)));

#define BC(x) __builtin_bit_cast(half2_t, x)

// raw barrier: LDS-visibility only, does NOT drain vmcnt (global prefetch
// loads stay in flight across it; compiler inserts the vmcnt wait at the
// actual register consumer).
#define BAR() asm volatile("s_waitcnt lgkmcnt(0)\n\ts_barrier" ::: "memory")

__device__ __forceinline__ float fdot2f(half2_t a, half2_t b, float c) {
#if defined(__has_builtin)
#if __has_builtin(__builtin_amdgcn_fdot2)
  return __builtin_amdgcn_fdot2(a, b, c, false);
#else
  return c + (float)a[0] * (float)b[0] + (float)a[1] * (float)b[1];
#endif
#else
  return c + (float)a[0] * (float)b[0] + (float)a[1] * (float)b[1];
#endif
}

__device__ __forceinline__ float rcp_(float x) { return __builtin_amdgcn_rcpf(x); }
__device__ __forceinline__ float sigmoid_(float x) { return rcp_(1.f + __expf(-x)); }
__device__ __forceinline__ float tanh_(float x) {
  float ax = fabsf(x);
  float e = __expf(-2.f * ax);             // in (0,1], no overflow ever
  float r = (1.f - e) * rcp_(1.f + e);
  return copysignf(r, x);
}

__device__ __forceinline__ float readlane_f(float x, int lane) {
#if defined(__has_builtin)
#if __has_builtin(__builtin_amdgcn_readlane)
  return __builtin_bit_cast(float, __builtin_amdgcn_readlane(__builtin_bit_cast(int, x), lane));
#else
  return __shfl(x, lane);
#endif
#else
  return __shfl(x, lane);
#endif
}

#if defined(__has_builtin)
#if __has_builtin(__builtin_amdgcn_update_dpp)
#define HAVE_DPP 1
#endif
#endif

__device__ __forceinline__ float wave_sum64_bcast(float x) {
#ifdef HAVE_DPP
#define DPP_ADD(ctrl)                                                          \
  {                                                                            \
    int _t = __builtin_amdgcn_update_dpp(0, __builtin_bit_cast(int, x), ctrl,  \
                                         0xf, 0xf, true);                      \
    x += __builtin_bit_cast(float, _t);                                        \
  }
  DPP_ADD(0x111)  // row_shr:1
  DPP_ADD(0x112)  // row_shr:2
  DPP_ADD(0x114)  // row_shr:4
  DPP_ADD(0x118)  // row_shr:8
  DPP_ADD(0x142)  // row_bcast:15
  DPP_ADD(0x143)  // row_bcast:31
#undef DPP_ADD
  return readlane_f(x, 63);
#else
#pragma unroll
  for (int s = 1; s <= 32; s <<= 1) x += __shfl_xor(x, s);
  return x;
#endif
}

// unit-major permutation of the 4H gate-row index: j (= g*128+u) -> 4u+g
__device__ __host__ __forceinline__ int permj(int j) {
  return ((j & 127) << 2) | (j >> 7);
}

// ---------------------------------------------------------------------------
// Kernel A: trans = row-softmax(transition); W16 = (f16)W_ih with rows
// PERMUTED to unit-major order (row' = 4u+g) so gemm_in's output precomp
// is unit-major with coalesced stores.
// ---------------------------------------------------------------------------
__global__ __launch_bounds__(128) void prep_kernel(
    const float* __restrict__ transition, const float* __restrict__ W_ih,
    float* __restrict__ trans, _Float16* __restrict__ W16) {
  const int bid = blockIdx.x, t = threadIdx.x;
  if (bid < 128) {
    __shared__ float red[2];
    float v = transition[bid * HH + t];
    float m = v;
#pragma unroll
    for (int s = 32; s >= 1; s >>= 1) m = fmaxf(m, __shfl_xor(m, s));
    if ((t & 63) == 0) red[t >> 6] = m;
    __syncthreads();
    m = fmaxf(red[0], red[1]);
    float e = __expf(v - m);
    float s = e;
#pragma unroll
    for (int k = 32; k >= 1; k >>= 1) s += __shfl_xor(s, k);
    __syncthreads();  // protect red before reuse
    if ((t & 63) == 0) red[t >> 6] = s;
    __syncthreads();
    trans[bid * HH + t] = e * rcp_(red[0] + red[1]);
  } else {
    const int base = (bid - 128) * 1024 + t * 8;  // 131072 total elems
    const int row = base >> 8;     // constant per thread (8 | 256)
    const int col = base & 255;
    float4 v0 = *(const float4*)(W_ih + base);
    float4 v1 = *(const float4*)(W_ih + base + 4);
    f16x8 h;
    h[0] = (_Float16)v0.x; h[1] = (_Float16)v0.y;
    h[2] = (_Float16)v0.z; h[3] = (_Float16)v0.w;
    h[4] = (_Float16)v1.x; h[5] = (_Float16)v1.y;
    h[6] = (_Float16)v1.z; h[7] = (_Float16)v1.w;
    *(f16x8*)(W16 + (size_t)permj(row) * EE + col) = h;
  }
}

// ---------------------------------------------------------------------------
// Kernel B: precomp[m][j'] = sum_e inputs[m][e]*W_ih[orig(j')][e] + bias.
// W16 rows are already permuted, so output cols are unit-major; only the
// bias lookup needs the inverse permutation.  Stores stay coalesced.
// ---------------------------------------------------------------------------
__global__ __launch_bounds__(256) void gemm_in(
    const float* __restrict__ A, const _Float16* __restrict__ W16,
    const float* __restrict__ b_ih, const float* __restrict__ b_hh,
    float* __restrict__ out) {
  __shared__ _Float16 As[64][264];  // K=256 + 8 pad (16B-aligned rows)
  const int t = threadIdx.x;
  const int m0 = blockIdx.x * 64;
  const int n0 = blockIdx.y * 256;
  {
    const int c4 = t & 63, r0 = t >> 6;
#pragma unroll
    for (int p = 0; p < 16; ++p) {
      const int row = r0 + 4 * p;
      float4 v = *(const float4*)(A + (size_t)(m0 + row) * EE + c4 * 4);
      f16x4 h;
      h[0] = (_Float16)v.x; h[1] = (_Float16)v.y;
      h[2] = (_Float16)v.z; h[3] = (_Float16)v.w;
      *(f16x4*)&As[row][c4 * 4] = h;
    }
  }
  __syncthreads();
  const int w = t >> 6, L = t & 63;
  const int lrow = L & 15, quad = L >> 4, lk = quad * 8;
  f32x4 acc[4][4] = {};
  const _Float16* Wbase = W16 + (size_t)(n0 + w * 64) * EE;
#pragma unroll
  for (int kc = 0; kc < 8; ++kc) {
    f16x8 a[4], bf[4];
#pragma unroll
    for (int mf = 0; mf < 4; ++mf)
      a[mf] = *(const f16x8*)&As[mf * 16 + lrow][kc * 32 + lk];
#pragma unroll
    for (int nf = 0; nf < 4; ++nf)
      bf[nf] = *(const f16x8*)(Wbase + (size_t)(nf * 16 + lrow) * EE + kc * 32 + lk);
#pragma unroll
    for (int mf = 0; mf < 4; ++mf)
#pragma unroll
      for (int nf = 0; nf < 4; ++nf)
        acc[mf][nf] = __builtin_amdgcn_mfma_f32_16x16x32_f16(a[mf], bf[nf], acc[mf][nf], 0, 0, 0);
  }
#pragma unroll
  for (int nf = 0; nf < 4; ++nf) {
    const int j = n0 + w * 64 + nf * 16 + lrow;        // permuted col
    const int jo = ((j & 3) << 7) | (j >> 2);          // original gate index
    const float bias = b_ih[jo] + b_hh[jo];
#pragma unroll
    for (int mf = 0; mf < 4; ++mf) {
#pragma unroll
      for (int r = 0; r < 4; ++r) {  // C/D: row = quad*4 + r
        const int m = m0 + mf * 16 + quad * 4 + r;
        out[(size_t)m * G4 + j] = acc[mf][nf][r] + bias;
      }
    }
  }
}

// ---------------------------------------------------------------------------
// Kernel C: fused LSTM + softmax + CRF.  One 512-thread block per batch.
// GATE MATVEC VIA MFMA (16x16x32 f16): W_hh rows (unit-major, row'=4u+g)
// live in A-fragments in registers; h is the B operand -> a wave ingests all
// of h with 4 fragment reads instead of 16 broadcast b128 (the measured
// bottleneck: ~128 h-reads/step at ~11cy each).  All 16 B-columns read the
// same h, so every column of C is a valid copy of the matvec: cell update is
// IN-LANE (C reg r = gate r of unit 4T+q), lane-group c2=l15&3 processes
// tile c2 (uniform, no divergence), single ds_write_b16 publishes h.
// acc is initialized with precomp (C-input) -> free bias add.
// CRF dot / phase-3 softmax+CRF recursion kept verbatim from the verified R4.
// Raw lgkmcnt barriers keep the depth-2 precomp prefetch in flight.
// __launch_bounds__(512,1): 2nd arg = min BLOCKS/CU (R7 evidence) -> 1 block
// -> 2 waves/SIMD -> 256-VGPR cap (need ~180, no spill).
// ---------------------------------------------------------------------------
__global__ __launch_bounds__(512, 1) void lstm_crf(
    const float* __restrict__ precomp, const float* __restrict__ Whh,
    const float* __restrict__ trans, const int* __restrict__ labels,
    float* __restrict__ out_b) {
  const int b = blockIdx.x, t = threadIdx.x;
  const int w = t >> 6, l = t & 63, q = l >> 4, l15 = l & 15;
  const int c2 = l15 & 3;      // tile this lane finalizes in the cell phase
  const int g2 = t >> 7, jj = t & 127;  // CRF roles (quarter, unit)

  __shared__ __align__(16) _Float16 h_lds[2][HH];
  __shared__ __align__(16) _Float16 E_lds[HH];
  __shared__ __align__(16) float Spart[G4];   // [quarter*128 + unit]
  __shared__ int lab[TT];

  // --- one-time: W_hh A-fragments (rows' = 16T + l15, T = 4w+tf) -----------
  f16x8 wfr[4][4];
#pragma unroll
  for (int tf = 0; tf < 4; ++tf) {
    const int rowp = 16 * (4 * w + tf) + l15;   // unit-major row index
    const int u = rowp >> 2, g = rowp & 3;
    const float* src = Whh + (size_t)(g * HH + u) * HH;
#pragma unroll
    for (int kt = 0; kt < 4; ++kt) {
      const float* s8 = src + kt * 32 + q * 8;
      float4 v0 = *(const float4*)s8;
      float4 v1 = *(const float4*)(s8 + 4);
      f16x8 h8;
      h8[0] = (_Float16)v0.x; h8[1] = (_Float16)v0.y;
      h8[2] = (_Float16)v0.z; h8[3] = (_Float16)v0.w;
      h8[4] = (_Float16)v1.x; h8[5] = (_Float16)v1.y;
      h8[6] = (_Float16)v1.z; h8[7] = (_Float16)v1.w;
      wfr[tf][kt] = h8;
    }
  }
  // et[a] = exp(trans[g2*32+2a][jj]), exp(trans[g2*32+2a+1][jj])
  half2_t et[16];
#pragma unroll
  for (int a = 0; a < 16; ++a) {
    float e0 = __expf(trans[(g2 * 32 + 2 * a) * HH + jj]);
    float e1 = __expf(trans[(g2 * 32 + 2 * a + 1) * HH + jj]);
    half2_t h2; h2[0] = (_Float16)e0; h2[1] = (_Float16)e1;
    et[a] = h2;
  }
  lab[t] = labels[b * TT + t];
  if (t < HH) { h_lds[0][t] = (_Float16)0.f; E_lds[t] = (_Float16)0.f; }

  // wave-0 persistent CRF state (units 2t, 2t+1)
  float tr0x = 0.f, tr0y = 0.f, tr127x = 0.f, tr127y = 0.f;
  if (t < 64) {
    float2 v0 = *(const float2*)(trans + 2 * t);
    float2 v1 = *(const float2*)(trans + 127 * HH + 2 * t);
    tr0x = v0.x; tr0y = v0.y; tr127x = v1.x; tr127y = v1.y;
  }
  float cst = 0.f;   // cell state of unit 16w + 4*c2 + q
  float preA = 0.f, preB = 0.f, mused = 0.f, emit = 0.f;

  // precomp (unit-major cols): lane needs rows' 16T+4q..+3 = one float4/tile
  const float* pcb = precomp + (size_t)b * TT * G4 + 64 * w + 4 * q;
  f32x4 pc_cur[4], pc_nxt[4];
#pragma unroll
  for (int tf = 0; tf < 4; ++tf) pc_cur[tf] = *(const f32x4*)(pcb + 16 * tf);
  __syncthreads();

#pragma unroll 1
  for (int step = 0; step < TT; ++step) {
    const int pr = step & 1;
    const int sn = (step < TT - 1) ? step + 1 : step;
#pragma unroll
    for (int tf = 0; tf < 4; ++tf)
      pc_nxt[tf] = *(const f32x4*)(pcb + (size_t)sn * G4 + 16 * tf);
    // --- B-fragments of h (4 reads cover all of h for the whole wave) ------
    const f16x8 hb0 = *(const f16x8*)&h_lds[pr][q * 8];
    const f16x8 hb1 = *(const f16x8*)&h_lds[pr][32 + q * 8];
    const f16x8 hb2 = *(const f16x8*)&h_lds[pr][64 + q * 8];
    const f16x8 hb3 = *(const f16x8*)&h_lds[pr][96 + q * 8];
    // --- gate matvec: 4 row-tiles x 4 k-tiles, acc init = precomp ----------
    f32x4 a0 = pc_cur[0], a1 = pc_cur[1], a2 = pc_cur[2], a3 = pc_cur[3];
    a0 = __builtin_amdgcn_mfma_f32_16x16x32_f16(wfr[0][0], hb0, a0, 0, 0, 0);
    a1 = __builtin_amdgcn_mfma_f32_16x16x32_f16(wfr[1][0], hb0, a1, 0, 0, 0);
    a2 = __builtin_amdgcn_mfma_f32_16x16x32_f16(wfr[2][0], hb0, a2, 0, 0, 0);
    a3 = __builtin_amdgcn_mfma_f32_16x16x32_f16(wfr[3][0], hb0, a3, 0, 0, 0);
    a0 = __builtin_amdgcn_mfma_f32_16x16x32_f16(wfr[0][1], hb1, a0, 0, 0, 0);
    a1 = __builtin_amdgcn_mfma_f32_16x16x32_f16(wfr[1][1], hb1, a1, 0, 0, 0);
    a2 = __builtin_amdgcn_mfma_f32_16x16x32_f16(wfr[2][1], hb1, a2, 0, 0, 0);
    a3 = __builtin_amdgcn_mfma_f32_16x16x32_f16(wfr[3][1], hb1, a3, 0, 0, 0);
    a0 = __builtin_amdgcn_mfma_f32_16x16x32_f16(wfr[0][2], hb2, a0, 0, 0, 0);
    a1 = __builtin_amdgcn_mfma_f32_16x16x32_f16(wfr[1][2], hb2, a1, 0, 0, 0);
    a2 = __builtin_amdgcn_mfma_f32_16x16x32_f16(wfr[2][2], hb2, a2, 0, 0, 0);
    a3 = __builtin_amdgcn_mfma_f32_16x16x32_f16(wfr[3][2], hb2, a3, 0, 0, 0);
    a0 = __builtin_amdgcn_mfma_f32_16x16x32_f16(wfr[0][3], hb3, a0, 0, 0, 0);
    a1 = __builtin_amdgcn_mfma_f32_16x16x32_f16(wfr[1][3], hb3, a1, 0, 0, 0);
    a2 = __builtin_amdgcn_mfma_f32_16x16x32_f16(wfr[2][3], hb3, a2, 0, 0, 0);
    a3 = __builtin_amdgcn_mfma_f32_16x16x32_f16(wfr[3][3], hb3, a3, 0, 0, 0);
    // --- CRF quarter dot (verbatim R4) -------------------------------------
    float s0 = 0.f, s1 = 0.f;
    const float4* ev4 = (const float4*)E_lds + g2 * 4;
#pragma unroll
    for (int ec = 0; ec < 4; ++ec) {
      float4 eb = ev4[ec];
      s0 = fdot2f(et[4 * ec + 0], BC(eb.x), s0);
      s1 = fdot2f(et[4 * ec + 1], BC(eb.y), s1);
      s0 = fdot2f(et[4 * ec + 2], BC(eb.z), s0);
      s1 = fdot2f(et[4 * ec + 3], BC(eb.w), s1);
    }
    // --- cell update, in-lane (every col-group has valid data; each lane
    //     finalizes tile c2 -> only ~5 transcendentals per lane) ------------
    const f32x4 ac = (c2 == 0) ? a0 : (c2 == 1) ? a1 : (c2 == 2) ? a2 : a3;
    const float iv = sigmoid_(ac[0]);
    const float fv = sigmoid_(ac[1]);
    const float gv = tanh_(ac[2]);
    const float ov = sigmoid_(ac[3]);
    cst = fv * cst + iv * gv;
    const float hv = ov * tanh_(cst);
    if (l15 < 4) h_lds[pr ^ 1][16 * w + 4 * l15 + q] = (_Float16)hv;
    Spart[t] = s0 + s1;
    BAR();  // A: h_s + Spart visible
    // --- phase 3 (wave 0): softmax + CRF recursion (verbatim R4 core) ------
    if (t < 64) {
      const half2_t hp = *(const half2_t*)&h_lds[pr ^ 1][2 * t];
      const float h0 = (float)hp[0], h1 = (float)hp[1];
      const float e0 = __expf(h0), e1 = __expf(h1);  // |h|<1: no max-sub
      const float denom = wave_sum64_bcast(e0 + e1);
      const float rinv = rcp_(denom);
      const float p0 = e0 * rinv, p1 = e1 * rinv;
      const float2* s2p = (const float2*)Spart;
      float2 Sq0 = s2p[t], Sq1 = s2p[64 + t], Sq2 = s2p[128 + t], Sq3 = s2p[192 + t];
      const float Sa = (Sq0.x + Sq1.x) + (Sq2.x + Sq3.x);
      const float Sb = (Sq0.y + Sq1.y) + (Sq2.y + Sq3.y);
      const float lgSa = __logf(Sa), lgSb = __logf(Sb);
      const float lgS0 = readlane_f(lgSa, 0);      // unit 0's log S
      const int lb = lab[step];
      const float Mnext = (step == 0) ? 0.f : (mused + lgS0);
      preA = p0 + ((step == 0) ? tr0x : (mused + lgSa));
      preB = p1 + ((step == 0) ? tr0y : (mused + lgSb));
      if (2 * t == lb) emit += p0;
      if (2 * t + 1 == lb) emit += p1;
      half2_t Eh;
      Eh[0] = (_Float16)__expf(preA - Mnext);  // bounded ~[0.37, 7.4]
      Eh[1] = (_Float16)__expf(preB - Mnext);
      *(half2_t*)&E_lds[2 * t] = Eh;
      mused = Mnext;
    }
    BAR();  // C: E_s visible
#pragma unroll
    for (int tf = 0; tf < 4; ++tf) pc_cur[tf] = pc_nxt[tf];
  }
  // --- epilogue (wave 0): Ps = LSE(pre + trans[127]); out_b = Ps - emit ----
  if (t < 64) {
    float v0 = preA + tr127x, v1 = preB + tr127y;
    float m = fmaxf(v0, v1);
#pragma unroll
    for (int s = 1; s <= 32; s <<= 1) m = fmaxf(m, __shfl_xor(m, s));
    float ex = __expf(v0 - m) + __expf(v1 - m);
    float em = emit;
#pragma unroll
    for (int s = 1; s <= 32; s <<= 1) {
      ex += __shfl_xor(ex, s);
      em += __shfl_xor(em, s);
    }
    if (t == 0) out_b[b] = m + __logf(ex) - em;
  }
}

// ---------------------------------------------------------------------------
// Kernel D: total = sum_b out_b[b] - sum_{b,t<511} trans[l_t][l_{t+1}]
// ---------------------------------------------------------------------------
__global__ __launch_bounds__(512) void finalize_kernel(
    const float* __restrict__ trans, const int* __restrict__ labels,
    const float* __restrict__ out_b, float* __restrict__ d_out) {
  const int t = threadIdx.x;
  float a = 0.f;
  if (t < TT - 1) {
    for (int b = 0; b < BB; ++b) {
      const int l0 = labels[b * TT + t];
      const int l1 = labels[b * TT + t + 1];
      a += trans[l0 * HH + l1];
    }
  }
  float x = ((t < BB) ? out_b[t] : 0.f) - a;
  __shared__ float red[8];
#pragma unroll
  for (int s = 32; s >= 1; s >>= 1) x += __shfl_xor(x, s);
  if ((t & 63) == 0) red[t >> 6] = x;
  __syncthreads();
  if (t == 0) {
    float s = 0.f;
#pragma unroll
    for (int i = 0; i < 8; ++i) s += red[i];
    d_out[0] = s;
  }
}

// ---------------------------------------------------------------------------
extern "C" void kernel_launch(void* const* d_in, const int* in_sizes, int n_in,
                              void* d_out, int out_size, void* d_ws, size_t ws_size,
                              hipStream_t stream) {
  const float* inputs = (const float*)d_in[0];      // (64,512,256) f32
  const int* labels = (const int*)d_in[1];          // (64,512) i32
  const float* W_ih = (const float*)d_in[2];        // (512,256) f32
  const float* W_hh = (const float*)d_in[3];        // (512,128) f32
  const float* b_ih = (const float*)d_in[4];        // (512,) f32
  const float* b_hh = (const float*)d_in[5];        // (512,) f32
  const float* transition = (const float*)d_in[6];  // (128,128) f32

  char* ws = (char*)d_ws;
  float* precomp = (float*)ws;                           // 64 MiB
  float* trans = (float*)(ws + 67108864);                // 64 KiB
  _Float16* W16 = (_Float16*)(ws + 67108864 + 65536);    // 256 KiB
  float* out_b = (float*)(ws + 67108864 + 65536 + 262144);

  prep_kernel<<<256, 128, 0, stream>>>(transition, W_ih, trans, W16);
  gemm_in<<<dim3(512, 2), 256, 0, stream>>>(inputs, W16, b_ih, b_hh, precomp);
  lstm_crf<<<64, 512, 0, stream>>>(precomp, W_hh, trans, labels, out_b);
  finalize_kernel<<<1, 512, 0, stream>>>(trans, labels, out_b, (float*)d_out);
}

// Round 9
// 563.071 us; speedup vs baseline: 2.0599x; 1.0288x over previous
//
#include <hip/hip_runtime.h>
#include <hip/hip_bf16.h>
#include <cstdint>

// Problem constants: B=64, T=512, E=256, H=128, 4H=512.
#define BB 64
#define TT 512
#define EE 256
#define HH 128
#define G4 512

typedef _Float16 half2_t __attribute__((ext_vector_type(2)));
typedef _Float16 f16x4 __attribute__((ext_vector_type(4)));
typedef _Float16 f16x8 __attribute__((ext_vector_type(8)));
typedef float f32x4 __attribute__((ext_vector_type(4)));

#define BC(x) __builtin_bit_cast(half2_t, x)

// raw barrier: LDS-visibility only, does NOT drain vmcnt (global prefetch
// loads stay in flight across it).
#define BAR() asm volatile("s_waitcnt lgkmcnt(0)\n\ts_barrier" ::: "memory")

__device__ __forceinline__ float fdot2f(half2_t a, half2_t b, float c) {
#if defined(__has_builtin)
#if __has_builtin(__builtin_amdgcn_fdot2)
  return __builtin_amdgcn_fdot2(a, b, c, false);
#else
  return c + (float)a[0] * (float)b[0] + (float)a[1] * (float)b[1];
#endif
#else
  return c + (float)a[0] * (float)b[0] + (float)a[1] * (float)b[1];
#endif
}

__device__ __forceinline__ float rcp_(float x) { return __builtin_amdgcn_rcpf(x); }
__device__ __forceinline__ float sigmoid_(float x) { return rcp_(1.f + __expf(-x)); }
__device__ __forceinline__ float tanh_(float x) {
  float ax = fabsf(x);
  float e = __expf(-2.f * ax);             // in (0,1], no overflow ever
  float r = (1.f - e) * rcp_(1.f + e);
  return copysignf(r, x);
}

__device__ __forceinline__ float readlane_f(float x, int lane) {
#if defined(__has_builtin)
#if __has_builtin(__builtin_amdgcn_readlane)
  return __builtin_bit_cast(float, __builtin_amdgcn_readlane(__builtin_bit_cast(int, x), lane));
#else
  return __shfl(x, lane);
#endif
#else
  return __shfl(x, lane);
#endif
}

#if defined(__has_builtin)
#if __has_builtin(__builtin_amdgcn_update_dpp)
#define HAVE_DPP 1
#endif
#endif

__device__ __forceinline__ float wave_sum64_bcast(float x) {
#ifdef HAVE_DPP
#define DPP_ADD(ctrl)                                                          \
  {                                                                            \
    int _t = __builtin_amdgcn_update_dpp(0, __builtin_bit_cast(int, x), ctrl,  \
                                         0xf, 0xf, true);                      \
    x += __builtin_bit_cast(float, _t);                                        \
  }
  DPP_ADD(0x111)  // row_shr:1
  DPP_ADD(0x112)  // row_shr:2
  DPP_ADD(0x114)  // row_shr:4
  DPP_ADD(0x118)  // row_shr:8
  DPP_ADD(0x142)  // row_bcast:15
  DPP_ADD(0x143)  // row_bcast:31
#undef DPP_ADD
  return readlane_f(x, 63);
#else
#pragma unroll
  for (int s = 1; s <= 32; s <<= 1) x += __shfl_xor(x, s);
  return x;
#endif
}

// unit-major permutation of the 4H gate-row index: j (= g*128+u) -> 4u+g
__device__ __host__ __forceinline__ int permj(int j) {
  return ((j & 127) << 2) | (j >> 7);
}

// ---------------------------------------------------------------------------
// Kernel A: trans = row-softmax(transition); W16 = (f16)W_ih with rows
// permuted to unit-major order (row' = 4u+g) so precomp cols are unit-major.
// ---------------------------------------------------------------------------
__global__ __launch_bounds__(128) void prep_kernel(
    const float* __restrict__ transition, const float* __restrict__ W_ih,
    float* __restrict__ trans, _Float16* __restrict__ W16) {
  const int bid = blockIdx.x, t = threadIdx.x;
  if (bid < 128) {
    __shared__ float red[2];
    float v = transition[bid * HH + t];
    float m = v;
#pragma unroll
    for (int s = 32; s >= 1; s >>= 1) m = fmaxf(m, __shfl_xor(m, s));
    if ((t & 63) == 0) red[t >> 6] = m;
    __syncthreads();
    m = fmaxf(red[0], red[1]);
    float e = __expf(v - m);
    float s = e;
#pragma unroll
    for (int k = 32; k >= 1; k >>= 1) s += __shfl_xor(s, k);
    __syncthreads();  // protect red before reuse
    if ((t & 63) == 0) red[t >> 6] = s;
    __syncthreads();
    trans[bid * HH + t] = e * rcp_(red[0] + red[1]);
  } else {
    const int base = (bid - 128) * 1024 + t * 8;  // 131072 total elems
    const int row = base >> 8;
    const int col = base & 255;
    float4 v0 = *(const float4*)(W_ih + base);
    float4 v1 = *(const float4*)(W_ih + base + 4);
    f16x8 h;
    h[0] = (_Float16)v0.x; h[1] = (_Float16)v0.y;
    h[2] = (_Float16)v0.z; h[3] = (_Float16)v0.w;
    h[4] = (_Float16)v1.x; h[5] = (_Float16)v1.y;
    h[6] = (_Float16)v1.z; h[7] = (_Float16)v1.w;
    *(f16x8*)(W16 + (size_t)permj(row) * EE + col) = h;
  }
}

// ---------------------------------------------------------------------------
// Kernel B: precomp[m][j'] = sum_e inputs[m][e]*W_ih[orig(j')][e] + bias.
// ---------------------------------------------------------------------------
__global__ __launch_bounds__(256) void gemm_in(
    const float* __restrict__ A, const _Float16* __restrict__ W16,
    const float* __restrict__ b_ih, const float* __restrict__ b_hh,
    float* __restrict__ out) {
  __shared__ _Float16 As[64][264];  // K=256 + 8 pad
  const int t = threadIdx.x;
  const int m0 = blockIdx.x * 64;
  const int n0 = blockIdx.y * 256;
  {
    const int c4 = t & 63, r0 = t >> 6;
#pragma unroll
    for (int p = 0; p < 16; ++p) {
      const int row = r0 + 4 * p;
      float4 v = *(const float4*)(A + (size_t)(m0 + row) * EE + c4 * 4);
      f16x4 h;
      h[0] = (_Float16)v.x; h[1] = (_Float16)v.y;
      h[2] = (_Float16)v.z; h[3] = (_Float16)v.w;
      *(f16x4*)&As[row][c4 * 4] = h;
    }
  }
  __syncthreads();
  const int w = t >> 6, L = t & 63;
  const int lrow = L & 15, quad = L >> 4, lk = quad * 8;
  f32x4 acc[4][4] = {};
  const _Float16* Wbase = W16 + (size_t)(n0 + w * 64) * EE;
#pragma unroll
  for (int kc = 0; kc < 8; ++kc) {
    f16x8 a[4], bf[4];
#pragma unroll
    for (int mf = 0; mf < 4; ++mf)
      a[mf] = *(const f16x8*)&As[mf * 16 + lrow][kc * 32 + lk];
#pragma unroll
    for (int nf = 0; nf < 4; ++nf)
      bf[nf] = *(const f16x8*)(Wbase + (size_t)(nf * 16 + lrow) * EE + kc * 32 + lk);
#pragma unroll
    for (int mf = 0; mf < 4; ++mf)
#pragma unroll
      for (int nf = 0; nf < 4; ++nf)
        acc[mf][nf] = __builtin_amdgcn_mfma_f32_16x16x32_f16(a[mf], bf[nf], acc[mf][nf], 0, 0, 0);
  }
#pragma unroll
  for (int nf = 0; nf < 4; ++nf) {
    const int j = n0 + w * 64 + nf * 16 + lrow;        // permuted col
    const int jo = ((j & 3) << 7) | (j >> 2);          // original gate index
    const float bias = b_ih[jo] + b_hh[jo];
#pragma unroll
    for (int mf = 0; mf < 4; ++mf) {
#pragma unroll
      for (int r = 0; r < 4; ++r) {
        const int m = m0 + mf * 16 + quad * 4 + r;
        out[(size_t)m * G4 + j] = acc[mf][nf][r] + bias;
      }
    }
  }
}

// ---------------------------------------------------------------------------
// Kernel C: fused LSTM + softmax + CRF.  One 512-thread block per batch.
// MFMA gate matvec (R8, verified) + SINGLE-ACTIVATION-PER-LANE (new):
// every C-column holds a valid matvec copy, so lane (q,l15) takes tile
// tf=l15&3, gate gg=l15>>2 -> computes exactly ONE activation (2 TRANS ops,
// was 10/lane in R8 -> ~27 wave-TRANS/CU/step vs ~85, the R8-measured
// residual).  Activation written to gate-major act[gg*128+u] (4-way write
// conflict = ~free); cell+softmax+CRF recursion is the verified R4/R5
// phase 3 on wave 0 (conflict-free float2 reads, DPP wave-sum, in-register
// CRF state).  Raw lgkmcnt barriers; depth-2 precomp prefetch.
// __launch_bounds__(512,1): 1 block/CU -> 256-VGPR cap.
// ---------------------------------------------------------------------------
__global__ __launch_bounds__(512, 1) void lstm_crf(
    const float* __restrict__ precomp, const float* __restrict__ Whh,
    const float* __restrict__ trans, const int* __restrict__ labels,
    float* __restrict__ out_b) {
  const int b = blockIdx.x, t = threadIdx.x;
  const int w = t >> 6, l = t & 63, q = l >> 4, l15 = l & 15;
  const int tf_a = l15 & 3;        // tile this lane activates
  const int gg = l15 >> 2;         // gate this lane activates
  const int ua = 16 * w + 4 * tf_a + q;  // its unit
  const int g2 = t >> 7, jj = t & 127;   // CRF roles (quarter, unit)

  __shared__ __align__(16) _Float16 h_lds[2][HH];
  __shared__ __align__(16) _Float16 E_lds[HH];
  __shared__ __align__(16) float act[G4];     // [gate*128 + unit]
  __shared__ __align__(16) float Spart[G4];   // [quarter*128 + unit]
  __shared__ int lab[TT];

  // --- one-time: W_hh A-fragments (rows' = 16(4w+tf) + l15) ----------------
  f16x8 wfr[4][4];
#pragma unroll
  for (int tf = 0; tf < 4; ++tf) {
    const int rowp = 16 * (4 * w + tf) + l15;   // unit-major row index
    const int u = rowp >> 2, g = rowp & 3;
    const float* src = Whh + (size_t)(g * HH + u) * HH;
#pragma unroll
    for (int kt = 0; kt < 4; ++kt) {
      const float* s8 = src + kt * 32 + q * 8;
      float4 v0 = *(const float4*)s8;
      float4 v1 = *(const float4*)(s8 + 4);
      f16x8 h8;
      h8[0] = (_Float16)v0.x; h8[1] = (_Float16)v0.y;
      h8[2] = (_Float16)v0.z; h8[3] = (_Float16)v0.w;
      h8[4] = (_Float16)v1.x; h8[5] = (_Float16)v1.y;
      h8[6] = (_Float16)v1.z; h8[7] = (_Float16)v1.w;
      wfr[tf][kt] = h8;
    }
  }
  // et[a] = exp(trans[g2*32+2a][jj]), exp(trans[g2*32+2a+1][jj])
  half2_t et[16];
#pragma unroll
  for (int a = 0; a < 16; ++a) {
    float e0 = __expf(trans[(g2 * 32 + 2 * a) * HH + jj]);
    float e1 = __expf(trans[(g2 * 32 + 2 * a + 1) * HH + jj]);
    half2_t h2; h2[0] = (_Float16)e0; h2[1] = (_Float16)e1;
    et[a] = h2;
  }
  lab[t] = labels[b * TT + t];
  if (t < HH) { h_lds[0][t] = (_Float16)0.f; E_lds[t] = (_Float16)0.f; }

  // wave-0 persistent CRF + cell state (units 2t, 2t+1)
  float tr0x = 0.f, tr0y = 0.f, tr127x = 0.f, tr127y = 0.f;
  if (t < 64) {
    float2 v0 = *(const float2*)(trans + 2 * t);
    float2 v1 = *(const float2*)(trans + 127 * HH + 2 * t);
    tr0x = v0.x; tr0y = v0.y; tr127x = v1.x; tr127y = v1.y;
  }
  float c0 = 0.f, c1 = 0.f, preA = 0.f, preB = 0.f, mused = 0.f, emit = 0.f;

  // precomp (unit-major cols): lane needs rows' 64w+16tf+4q..+3 per tile
  const float* pcb = precomp + (size_t)b * TT * G4 + 64 * w + 4 * q;
  f32x4 pc_cur[4], pc_nxt[4];
#pragma unroll
  for (int tf = 0; tf < 4; ++tf) pc_cur[tf] = *(const f32x4*)(pcb + 16 * tf);
  __syncthreads();

#pragma unroll 1
  for (int step = 0; step < TT; ++step) {
    const int pr = step & 1;
    const int sn = (step < TT - 1) ? step + 1 : step;
#pragma unroll
    for (int tf = 0; tf < 4; ++tf)
      pc_nxt[tf] = *(const f32x4*)(pcb + (size_t)sn * G4 + 16 * tf);
    // --- B-fragments of h (4 reads cover all of h for the whole wave) ------
    const f16x8 hb0 = *(const f16x8*)&h_lds[pr][q * 8];
    const f16x8 hb1 = *(const f16x8*)&h_lds[pr][32 + q * 8];
    const f16x8 hb2 = *(const f16x8*)&h_lds[pr][64 + q * 8];
    const f16x8 hb3 = *(const f16x8*)&h_lds[pr][96 + q * 8];
    // --- gate matvec: 4 row-tiles x 4 k-tiles, acc init = precomp ----------
    f32x4 a0 = pc_cur[0], a1 = pc_cur[1], a2 = pc_cur[2], a3 = pc_cur[3];
    a0 = __builtin_amdgcn_mfma_f32_16x16x32_f16(wfr[0][0], hb0, a0, 0, 0, 0);
    a1 = __builtin_amdgcn_mfma_f32_16x16x32_f16(wfr[1][0], hb0, a1, 0, 0, 0);
    a2 = __builtin_amdgcn_mfma_f32_16x16x32_f16(wfr[2][0], hb0, a2, 0, 0, 0);
    a3 = __builtin_amdgcn_mfma_f32_16x16x32_f16(wfr[3][0], hb0, a3, 0, 0, 0);
    a0 = __builtin_amdgcn_mfma_f32_16x16x32_f16(wfr[0][1], hb1, a0, 0, 0, 0);
    a1 = __builtin_amdgcn_mfma_f32_16x16x32_f16(wfr[1][1], hb1, a1, 0, 0, 0);
    a2 = __builtin_amdgcn_mfma_f32_16x16x32_f16(wfr[2][1], hb1, a2, 0, 0, 0);
    a3 = __builtin_amdgcn_mfma_f32_16x16x32_f16(wfr[3][1], hb1, a3, 0, 0, 0);
    a0 = __builtin_amdgcn_mfma_f32_16x16x32_f16(wfr[0][2], hb2, a0, 0, 0, 0);
    a1 = __builtin_amdgcn_mfma_f32_16x16x32_f16(wfr[1][2], hb2, a1, 0, 0, 0);
    a2 = __builtin_amdgcn_mfma_f32_16x16x32_f16(wfr[2][2], hb2, a2, 0, 0, 0);
    a3 = __builtin_amdgcn_mfma_f32_16x16x32_f16(wfr[3][2], hb2, a3, 0, 0, 0);
    a0 = __builtin_amdgcn_mfma_f32_16x16x32_f16(wfr[0][3], hb3, a0, 0, 0, 0);
    a1 = __builtin_amdgcn_mfma_f32_16x16x32_f16(wfr[1][3], hb3, a1, 0, 0, 0);
    a2 = __builtin_amdgcn_mfma_f32_16x16x32_f16(wfr[2][3], hb3, a2, 0, 0, 0);
    a3 = __builtin_amdgcn_mfma_f32_16x16x32_f16(wfr[3][3], hb3, a3, 0, 0, 0);
    // --- CRF quarter dot (verbatim R4) -------------------------------------
    float s0 = 0.f, s1 = 0.f;
    const float4* ev4 = (const float4*)E_lds + g2 * 4;
#pragma unroll
    for (int ec = 0; ec < 4; ++ec) {
      float4 eb = ev4[ec];
      s0 = fdot2f(et[4 * ec + 0], BC(eb.x), s0);
      s1 = fdot2f(et[4 * ec + 1], BC(eb.y), s1);
      s0 = fdot2f(et[4 * ec + 2], BC(eb.z), s0);
      s1 = fdot2f(et[4 * ec + 3], BC(eb.w), s1);
    }
    // --- ONE activation per lane: value = a_{tf_a}[gg] ---------------------
    const f32x4 asel = (tf_a == 0) ? a0 : (tf_a == 1) ? a1 : (tf_a == 2) ? a2 : a3;
    const float gv = (gg == 0) ? asel[0] : (gg == 1) ? asel[1]
                   : (gg == 2) ? asel[2] : asel[3];
    const bool isg = (gg == 2);               // gate 2 = g -> tanh
    const float yy = isg ? (-2.f * fabsf(gv)) : (-gv);
    const float exv = __expf(yy);
    const float num = isg ? (1.f - exv) : 1.f;
    float av = num * rcp_(1.f + exv);
    av = isg ? copysignf(av, gv) : av;
    act[gg * HH + ua] = av;                   // gate-major, 4-way wr conflict
    Spart[t] = s0 + s1;
    BAR();  // A: act + Spart visible
    // --- phase 3 (wave 0): cell, softmax, CRF (verbatim R4/R5 core) --------
    if (t < 64) {
      const float2* a2p = (const float2*)act;
      float2 I = a2p[t], F = a2p[64 + t], G = a2p[128 + t], O = a2p[192 + t];
      c0 = F.x * c0 + I.x * G.x;
      c1 = F.y * c1 + I.y * G.y;
      const float h0 = O.x * tanh_(c0), h1 = O.y * tanh_(c1);
      const float e0 = __expf(h0), e1 = __expf(h1);  // |h|<1: no max-sub
      const float denom = wave_sum64_bcast(e0 + e1);
      const float rinv = rcp_(denom);
      const float p0 = e0 * rinv, p1 = e1 * rinv;
      const float2* s2p = (const float2*)Spart;
      float2 Sq0 = s2p[t], Sq1 = s2p[64 + t], Sq2 = s2p[128 + t], Sq3 = s2p[192 + t];
      const float Sa = (Sq0.x + Sq1.x) + (Sq2.x + Sq3.x);
      const float Sb = (Sq0.y + Sq1.y) + (Sq2.y + Sq3.y);
      const float lgSa = __logf(Sa), lgSb = __logf(Sb);
      const float lgS0 = readlane_f(lgSa, 0);      // unit 0's log S
      const int lb = lab[step];
      const float Mnext = (step == 0) ? 0.f : (mused + lgS0);
      preA = p0 + ((step == 0) ? tr0x : (mused + lgSa));
      preB = p1 + ((step == 0) ? tr0y : (mused + lgSb));
      if (2 * t == lb) emit += p0;
      if (2 * t + 1 == lb) emit += p1;
      half2_t Eh;
      Eh[0] = (_Float16)__expf(preA - Mnext);  // bounded ~[0.37, 7.4]
      Eh[1] = (_Float16)__expf(preB - Mnext);
      *(half2_t*)&E_lds[2 * t] = Eh;
      half2_t Hh;
      Hh[0] = (_Float16)h0; Hh[1] = (_Float16)h1;
      *(half2_t*)&h_lds[pr ^ 1][2 * t] = Hh;
      mused = Mnext;
    }
    BAR();  // C: h + E visible
#pragma unroll
    for (int tf = 0; tf < 4; ++tf) pc_cur[tf] = pc_nxt[tf];
  }
  // --- epilogue (wave 0): Ps = LSE(pre + trans[127]); out_b = Ps - emit ----
  if (t < 64) {
    float v0 = preA + tr127x, v1 = preB + tr127y;
    float m = fmaxf(v0, v1);
#pragma unroll
    for (int s = 1; s <= 32; s <<= 1) m = fmaxf(m, __shfl_xor(m, s));
    float ex = __expf(v0 - m) + __expf(v1 - m);
    float em = emit;
#pragma unroll
    for (int s = 1; s <= 32; s <<= 1) {
      ex += __shfl_xor(ex, s);
      em += __shfl_xor(em, s);
    }
    if (t == 0) out_b[b] = m + __logf(ex) - em;
  }
}

// ---------------------------------------------------------------------------
// Kernel D: total = sum_b out_b[b] - sum_{b,t<511} trans[l_t][l_{t+1}]
// ---------------------------------------------------------------------------
__global__ __launch_bounds__(512) void finalize_kernel(
    const float* __restrict__ trans, const int* __restrict__ labels,
    const float* __restrict__ out_b, float* __restrict__ d_out) {
  const int t = threadIdx.x;
  float a = 0.f;
  if (t < TT - 1) {
    for (int b = 0; b < BB; ++b) {
      const int l0 = labels[b * TT + t];
      const int l1 = labels[b * TT + t + 1];
      a += trans[l0 * HH + l1];
    }
  }
  float x = ((t < BB) ? out_b[t] : 0.f) - a;
  __shared__ float red[8];
#pragma unroll
  for (int s = 32; s >= 1; s >>= 1) x += __shfl_xor(x, s);
  if ((t & 63) == 0) red[t >> 6] = x;
  __syncthreads();
  if (t == 0) {
    float s = 0.f;
#pragma unroll
    for (int i = 0; i < 8; ++i) s += red[i];
    d_out[0] = s;
  }
}

// ---------------------------------------------------------------------------
extern "C" void kernel_launch(void* const* d_in, const int* in_sizes, int n_in,
                              void* d_out, int out_size, void* d_ws, size_t ws_size,
                              hipStream_t stream) {
  const float* inputs = (const float*)d_in[0];      // (64,512,256) f32
  const int* labels = (const int*)d_in[1];          // (64,512) i32
  const float* W_ih = (const float*)d_in[2];        // (512,256) f32
  const float* W_hh = (const float*)d_in[3];        // (512,128) f32
  const float* b_ih = (const float*)d_in[4];        // (512,) f32
  const float* b_hh = (const float*)d_in[5];        // (512,) f32
  const float* transition = (const float*)d_in[6];  // (128,128) f32

  char* ws = (char*)d_ws;
  float* precomp = (float*)ws;                           // 64 MiB
  float* trans = (float*)(ws + 67108864);                // 64 KiB
  _Float16* W16 = (_Float16*)(ws + 67108864 + 65536);    // 256 KiB
  float* out_b = (float*)(ws + 67108864 + 65536 + 262144);

  prep_kernel<<<256, 128, 0, stream>>>(transition, W_ih, trans, W16);
  gemm_in<<<dim3(512, 2), 256, 0, stream>>>(inputs, W16, b_ih, b_hh, precomp);
  lstm_crf<<<64, 512, 0, stream>>>(precomp, W_hh, trans, labels, out_b);
  finalize_kernel<<<1, 512, 0, stream>>>(trans, labels, out_b, (float*)d_out);
}